// Round 28
// baseline (157.014 us; speedup 1.0000x reference)
//
#include <hip/hip_runtime.h>
#include <hip/hip_cooperative_groups.h>

namespace cg = cooperative_groups;

#define LOG2E 1.4426950408889634f
#define TWO_LOG2E 2.885390081777927f

__device__ __forceinline__ float fast_exp2(float x) { return __builtin_amdgcn_exp2f(x); }
__device__ __forceinline__ float fast_rcp(float x)  { return __builtin_amdgcn_rcpf(x); }

// paired-rcp: s0/A + s1/B with A=q0*k0+1, B=q1*k1+1
__device__ __forceinline__ void term2(float s0, float s1, float qx, float qy,
                                      float kx, float ky, float& acc) {
    const float A = fmaf(qx, kx, 1.f);
    const float B = fmaf(qy, ky, 1.f);
    acc = fmaf(fmaf(s1, A, s0 * B), fast_rcp(A * B), acc);
}

// ---------------------------------------------------------------------------
// MEGA kernel (cooperative): Phase 0 = projections (R25's proven proj, two
// 256-thread units per block; unit pair (2bx,2bx+1) is always same-type so
// block barrier counts match), grid.sync(), Phase 1 = fused scores+softmax+PV
// (R24/R25's proven 44.2us body verbatim). Eliminates 2 kernel boundaries
// (~11us of the 61.6us total).
// Grid 256 x 512thr, 1 block/CU, LDS 69KB (union of phases), VGPR cap 128.
// ---------------------------------------------------------------------------
#define EQ_ST 260
#define SS_ST 520
// phase-1 LDS layout offsets (floats)
#define OFF_EQ   0            // 8*260   = 2080
#define OFF_SC   2080         // 256
#define OFF_ST   2336         // 8*520   = 4160
#define OFF_RED  6496         // 32*256  = 8192
#define OFF_INV  14688        // 8
#define SMEM_FLOATS 17664     // phase-0 needs 2*8832

__global__ void __launch_bounds__(512, 2) mega_kernel(
    const float* __restrict__ query, const float* __restrict__ value,
    const float* __restrict__ Wq, const float* __restrict__ Wv,
    const float* __restrict__ scale,
    float* __restrict__ eqbuf, float* __restrict__ ekT,
    float* __restrict__ attn, float* __restrict__ out)
{
    __shared__ float smem[SMEM_FLOATS];   // 69KB

    const int bx = blockIdx.x;
    const int t = threadIdx.x;

    // ================= Phase 0: projections =================
    {
        const int half = t >> 8, tt = t & 255;
        const int unit = 2 * bx + half;          // 0..511
        float* sb = smem + half * 8832;

        if (unit < 256) {
            // ---- eq unit: 8 query rows ----
            const int row0 = unit * 8;
            const float4* s4 = (const float4*)(query + (size_t)row0 * 256);
            float4* l4 = (float4*)sb;
            l4[tt] = s4[tt];
            l4[tt + 256] = s4[tt + 256];
            __syncthreads();

            float acc[8];
#pragma unroll
            for (int r = 0; r < 8; ++r) acc[r] = 0.f;

            for (int d = 0; d < 256; d += 4) {
                const float w0 = Wq[(d + 0) * 256 + tt];
                const float w1 = Wq[(d + 1) * 256 + tt];
                const float w2 = Wq[(d + 2) * 256 + tt];
                const float w3 = Wq[(d + 3) * 256 + tt];
#pragma unroll
                for (int r = 0; r < 8; ++r) {
                    const float4 v = *(const float4*)&sb[r * 256 + d];
                    acc[r] = fmaf(v.x, w0, acc[r]);
                    acc[r] = fmaf(v.y, w1, acc[r]);
                    acc[r] = fmaf(v.z, w2, acc[r]);
                    acc[r] = fmaf(v.w, w3, acc[r]);
                }
            }
            float* dst = eqbuf + (size_t)row0 * 256;
#pragma unroll
            for (int r = 0; r < 8; ++r) dst[r * 256 + tt] = fast_exp2(acc[r] * TWO_LOG2E);
        } else {
            // ---- ekT unit: 64k x 32dout tile, transposed via LDS ----
            float* v_lds = sb;            // 64*68 = 4352
            float* w_lds = sb + 4352;     // 64*36 = 2304
            float* t_lds = sb + 6656;     // 32*68 = 2176
            const int bi = unit - 256;
            const int kt = bi >> 3, dt = bi & 7;
            const int gk0 = kt * 64;
            const int bb = gk0 >> 9, kin0 = gk0 & 511;
            const int dout0 = dt * 32;
            const int kp = tt >> 3, dg = tt & 7;

            float acc[2][4];
#pragma unroll
            for (int i = 0; i < 2; ++i)
#pragma unroll
                for (int j = 0; j < 4; ++j) acc[i][j] = 0.f;

            for (int dc = 0; dc < 256; dc += 64) {
                __syncthreads();
#pragma unroll
                for (int l = 0; l < 4; ++l) {
                    const int idx = tt + 256 * l;
                    const int r = idx >> 4, c4 = (idx & 15) * 4;
                    *(float4*)&v_lds[r * 68 + c4] =
                        *(const float4*)&value[(size_t)(gk0 + r) * 256 + dc + c4];
                }
#pragma unroll
                for (int l = 0; l < 2; ++l) {
                    const int idx = tt + 256 * l;
                    const int r = idx >> 3, c4 = (idx & 7) * 4;
                    *(float4*)&w_lds[r * 36 + c4] =
                        *(const float4*)&Wv[(size_t)(dc + r) * 256 + dout0 + c4];
                }
                __syncthreads();

#pragma unroll 8
                for (int din = 0; din < 64; ++din) {
                    const float v0 = v_lds[(2 * kp + 0) * 68 + din];
                    const float v1 = v_lds[(2 * kp + 1) * 68 + din];
                    const float4 wv = *(const float4*)&w_lds[din * 36 + 4 * dg];
                    acc[0][0] = fmaf(v0, wv.x, acc[0][0]);
                    acc[0][1] = fmaf(v0, wv.y, acc[0][1]);
                    acc[0][2] = fmaf(v0, wv.z, acc[0][2]);
                    acc[0][3] = fmaf(v0, wv.w, acc[0][3]);
                    acc[1][0] = fmaf(v1, wv.x, acc[1][0]);
                    acc[1][1] = fmaf(v1, wv.y, acc[1][1]);
                    acc[1][2] = fmaf(v1, wv.z, acc[1][2]);
                    acc[1][3] = fmaf(v1, wv.w, acc[1][3]);
                }
            }
            __syncthreads();
#pragma unroll
            for (int i = 0; i < 2; ++i)
#pragma unroll
                for (int j = 0; j < 4; ++j)
                    t_lds[(4 * dg + j) * 68 + 2 * kp + i] =
                        fast_exp2(acc[i][j] * TWO_LOG2E);
            __syncthreads();
#pragma unroll
            for (int l = 0; l < 2; ++l) {
                const int idx = tt + 256 * l;
                const int row = idx >> 4, c4 = (idx & 15) * 4;
                *(float4*)&ekT[(size_t)bb * 131072 + (size_t)(dout0 + row) * 512 + kin0 + c4] =
                    *(const float4*)&t_lds[row * 68 + c4];
            }
        }
    }

    __threadfence();
    cg::this_grid().sync();

    // ================= Phase 1: fused scores + softmax + PV =================
    float* eq_lds  = smem + OFF_EQ;
    float* sc_lds  = smem + OFF_SC;
    float* s_tile  = smem + OFF_ST;
    float* red     = smem + OFF_RED;
    float* inv_lds = smem + OFF_INV;

    const int w = t >> 6, lane = t & 63;
    const int qg = w >> 2;
    const int kg = ((w & 3) << 6) + lane;
    const int k0 = 2 * kg;
    const int qt = bx & 63, b = bx >> 6;
    const int q0 = qt * 8;

    // stage eq (8x256) and scale
    {
        const int row = t >> 6, c = t & 63;
        const float4 v = ((const float4*)(eqbuf + (size_t)(b * 512 + q0) * 256))[row * 64 + c];
        *(float4*)&eq_lds[row * EQ_ST + 4 * c] = v;
    }
    if (t < 256) sc_lds[t] = -2.f * scale[t];
    __syncthreads();

    // ---- scores, full d, NO barriers, depth-2 pipeline (proven 44.2us) ----
    const float* ekTb = ekT + (size_t)b * 131072 + k0;
    const float* q0r = &eq_lds[(4 * qg + 0) * EQ_ST];
    const float* q1r = &eq_lds[(4 * qg + 1) * EQ_ST];
    const float* q2r = &eq_lds[(4 * qg + 2) * EQ_ST];
    const float* q3r = &eq_lds[(4 * qg + 3) * EQ_ST];

    float a00 = 0.f, a01 = 0.f, a10 = 0.f, a11 = 0.f;
    float a20 = 0.f, a21 = 0.f, a30 = 0.f, a31 = 0.f;

    float4 svA  = *(const float4*)&sc_lds[0];
    float4 qv0A = *(const float4*)&q0r[0];
    float4 qv1A = *(const float4*)&q1r[0];
    float4 qv2A = *(const float4*)&q2r[0];
    float4 qv3A = *(const float4*)&q3r[0];
    float2 k0A = *(const float2*)&ekTb[(size_t)0 * 512];
    float2 k1A = *(const float2*)&ekTb[(size_t)1 * 512];
    float2 k2A = *(const float2*)&ekTb[(size_t)2 * 512];
    float2 k3A = *(const float2*)&ekTb[(size_t)3 * 512];

    float4 svB  = *(const float4*)&sc_lds[4];
    float4 qv0B = *(const float4*)&q0r[4];
    float4 qv1B = *(const float4*)&q1r[4];
    float4 qv2B = *(const float4*)&q2r[4];
    float4 qv3B = *(const float4*)&q3r[4];
    float2 k0B = *(const float2*)&ekTb[(size_t)4 * 512];
    float2 k1B = *(const float2*)&ekTb[(size_t)5 * 512];
    float2 k2B = *(const float2*)&ekTb[(size_t)6 * 512];
    float2 k3B = *(const float2*)&ekTb[(size_t)7 * 512];

#pragma unroll 2
    for (int d = 0; d < 256; d += 8) {
        {
            const float4 csv = svA, c0 = qv0A, c1 = qv1A, c2 = qv2A, c3 = qv3A;
            const float2 ck0 = k0A, ck1 = k1A, ck2 = k2A, ck3 = k3A;
            if (d < 248) {
                const int dn = d + 8;
                svA  = *(const float4*)&sc_lds[dn];
                qv0A = *(const float4*)&q0r[dn];
                qv1A = *(const float4*)&q1r[dn];
                qv2A = *(const float4*)&q2r[dn];
                qv3A = *(const float4*)&q3r[dn];
                k0A = *(const float2*)&ekTb[(size_t)(dn + 0) * 512];
                k1A = *(const float2*)&ekTb[(size_t)(dn + 1) * 512];
                k2A = *(const float2*)&ekTb[(size_t)(dn + 2) * 512];
                k3A = *(const float2*)&ekTb[(size_t)(dn + 3) * 512];
            }
            term2(csv.x, csv.y, c0.x, c0.y, ck0.x, ck1.x, a00);
            term2(csv.z, csv.w, c0.z, c0.w, ck2.x, ck3.x, a00);
            term2(csv.x, csv.y, c0.x, c0.y, ck0.y, ck1.y, a01);
            term2(csv.z, csv.w, c0.z, c0.w, ck2.y, ck3.y, a01);
            term2(csv.x, csv.y, c1.x, c1.y, ck0.x, ck1.x, a10);
            term2(csv.z, csv.w, c1.z, c1.w, ck2.x, ck3.x, a10);
            term2(csv.x, csv.y, c1.x, c1.y, ck0.y, ck1.y, a11);
            term2(csv.z, csv.w, c1.z, c1.w, ck2.y, ck3.y, a11);
            term2(csv.x, csv.y, c2.x, c2.y, ck0.x, ck1.x, a20);
            term2(csv.z, csv.w, c2.z, c2.w, ck2.x, ck3.x, a20);
            term2(csv.x, csv.y, c2.x, c2.y, ck0.y, ck1.y, a21);
            term2(csv.z, csv.w, c2.z, c2.w, ck2.y, ck3.y, a21);
            term2(csv.x, csv.y, c3.x, c3.y, ck0.x, ck1.x, a30);
            term2(csv.z, csv.w, c3.z, c3.w, ck2.x, ck3.x, a30);
            term2(csv.x, csv.y, c3.x, c3.y, ck0.y, ck1.y, a31);
            term2(csv.z, csv.w, c3.z, c3.w, ck2.y, ck3.y, a31);
        }
        {
            const float4 csv = svB, c0 = qv0B, c1 = qv1B, c2 = qv2B, c3 = qv3B;
            const float2 ck0 = k0B, ck1 = k1B, ck2 = k2B, ck3 = k3B;
            if (d < 244) {
                const int dn = d + 12;
                svB  = *(const float4*)&sc_lds[dn];
                qv0B = *(const float4*)&q0r[dn];
                qv1B = *(const float4*)&q1r[dn];
                qv2B = *(const float4*)&q2r[dn];
                qv3B = *(const float4*)&q3r[dn];
                k0B = *(const float2*)&ekTb[(size_t)(dn + 0) * 512];
                k1B = *(const float2*)&ekTb[(size_t)(dn + 1) * 512];
                k2B = *(const float2*)&ekTb[(size_t)(dn + 2) * 512];
                k3B = *(const float2*)&ekTb[(size_t)(dn + 3) * 512];
            }
            term2(csv.x, csv.y, c0.x, c0.y, ck0.x, ck1.x, a00);
            term2(csv.z, csv.w, c0.z, c0.w, ck2.x, ck3.x, a00);
            term2(csv.x, csv.y, c0.x, c0.y, ck0.y, ck1.y, a01);
            term2(csv.z, csv.w, c0.z, c0.w, ck2.y, ck3.y, a01);
            term2(csv.x, csv.y, c1.x, c1.y, ck0.x, ck1.x, a10);
            term2(csv.z, csv.w, c1.z, c1.w, ck2.x, ck3.x, a10);
            term2(csv.x, csv.y, c1.x, c1.y, ck0.y, ck1.y, a11);
            term2(csv.z, csv.w, c1.z, c1.w, ck2.y, ck3.y, a11);
            term2(csv.x, csv.y, c2.x, c2.y, ck0.x, ck1.x, a20);
            term2(csv.z, csv.w, c2.z, c2.w, ck2.x, ck3.x, a20);
            term2(csv.x, csv.y, c2.x, c2.y, ck0.y, ck1.y, a21);
            term2(csv.z, csv.w, c2.z, c2.w, ck2.y, ck3.y, a21);
            term2(csv.x, csv.y, c3.x, c3.y, ck0.x, ck1.x, a30);
            term2(csv.z, csv.w, c3.z, c3.w, ck2.x, ck3.x, a30);
            term2(csv.x, csv.y, c3.x, c3.y, ck0.y, ck1.y, a31);
            term2(csv.z, csv.w, c3.z, c3.w, ck2.y, ck3.y, a31);
        }
    }

    *(float2*)&s_tile[(4 * qg + 0) * SS_ST + k0] = make_float2(a00, a01);
    *(float2*)&s_tile[(4 * qg + 1) * SS_ST + k0] = make_float2(a10, a11);
    *(float2*)&s_tile[(4 * qg + 2) * SS_ST + k0] = make_float2(a20, a21);
    *(float2*)&s_tile[(4 * qg + 3) * SS_ST + k0] = make_float2(a30, a31);
    __syncthreads();

    // ---- softmax (wave w = q-row w), attn write ----
    {
        float x[8];
        float m = -1e30f;
#pragma unroll
        for (int j = 0; j < 8; ++j) {
            x[j] = s_tile[w * SS_ST + 64 * j + lane];
            m = fmaxf(m, x[j]);
        }
#pragma unroll
        for (int off = 32; off; off >>= 1) m = fmaxf(m, __shfl_xor(m, off));

        float sum = 0.f;
#pragma unroll
        for (int j = 0; j < 8; ++j) { x[j] = fast_exp2((x[j] - m) * LOG2E); sum += x[j]; }
#pragma unroll
        for (int off = 32; off; off >>= 1) sum += __shfl_xor(sum, off);
        const float inv = fast_rcp(sum);

        float* arow = attn + (size_t)(b * 512 + q0 + w) * 512;
#pragma unroll
        for (int j = 0; j < 8; ++j) {
            s_tile[w * SS_ST + 64 * j + lane] = x[j];
            arow[64 * j + lane] = x[j] * inv;
        }
        if (lane == 0) inv_lds[w] = inv;
    }
    __syncthreads();

    // ---- PV, wave w owns k in [64w, 64w+64) ----
    float4 acc[8];
#pragma unroll
    for (int r = 0; r < 8; ++r) acc[r] = make_float4(0.f, 0.f, 0.f, 0.f);

    const float* vbase = value + (size_t)(b * 512 + 64 * w) * 256;
    for (int k4 = 0; k4 < 64; k4 += 4) {
        const float4 v0 = *(const float4*)&vbase[(k4 + 0) * 256 + lane * 4];
        const float4 v1 = *(const float4*)&vbase[(k4 + 1) * 256 + lane * 4];
        const float4 v2 = *(const float4*)&vbase[(k4 + 2) * 256 + lane * 4];
        const float4 v3 = *(const float4*)&vbase[(k4 + 3) * 256 + lane * 4];
#pragma unroll
        for (int r = 0; r < 8; ++r) {
            const float4 s4 = *(const float4*)&s_tile[r * SS_ST + 64 * w + k4];
            acc[r].x = fmaf(s4.x, v0.x, acc[r].x); acc[r].y = fmaf(s4.x, v0.y, acc[r].y);
            acc[r].z = fmaf(s4.x, v0.z, acc[r].z); acc[r].w = fmaf(s4.x, v0.w, acc[r].w);
            acc[r].x = fmaf(s4.y, v1.x, acc[r].x); acc[r].y = fmaf(s4.y, v1.y, acc[r].y);
            acc[r].z = fmaf(s4.y, v1.z, acc[r].z); acc[r].w = fmaf(s4.y, v1.w, acc[r].w);
            acc[r].x = fmaf(s4.z, v2.x, acc[r].x); acc[r].y = fmaf(s4.z, v2.y, acc[r].y);
            acc[r].z = fmaf(s4.z, v2.z, acc[r].z); acc[r].w = fmaf(s4.z, v2.w, acc[r].w);
            acc[r].x = fmaf(s4.w, v3.x, acc[r].x); acc[r].y = fmaf(s4.w, v3.y, acc[r].y);
            acc[r].z = fmaf(s4.w, v3.z, acc[r].z); acc[r].w = fmaf(s4.w, v3.w, acc[r].w);
        }
    }

    // ---- tree reduce 8 -> 1 ----
    if (w >= 4) {
#pragma unroll
        for (int r = 0; r < 8; ++r)
            *(float4*)&red[((w - 4) * 8 + r) * 256 + lane * 4] = acc[r];
    }
    __syncthreads();
    if (w < 4) {
#pragma unroll
        for (int r = 0; r < 8; ++r) {
            const float4 o = *(const float4*)&red[(w * 8 + r) * 256 + lane * 4];
            acc[r].x += o.x; acc[r].y += o.y; acc[r].z += o.z; acc[r].w += o.w;
        }
    }
    __syncthreads();
    if (w >= 2 && w < 4) {
#pragma unroll
        for (int r = 0; r < 8; ++r)
            *(float4*)&red[((w - 2) * 8 + r) * 256 + lane * 4] = acc[r];
    }
    __syncthreads();
    if (w < 2) {
#pragma unroll
        for (int r = 0; r < 8; ++r) {
            const float4 o = *(const float4*)&red[(w * 8 + r) * 256 + lane * 4];
            acc[r].x += o.x; acc[r].y += o.y; acc[r].z += o.z; acc[r].w += o.w;
        }
    }
    __syncthreads();
    if (w == 1) {
#pragma unroll
        for (int r = 0; r < 8; ++r)
            *(float4*)&red[r * 256 + lane * 4] = acc[r];
    }
    __syncthreads();
    if (w == 0) {
#pragma unroll
        for (int r = 0; r < 8; ++r) {
            const float4 o = *(const float4*)&red[r * 256 + lane * 4];
            const float iv = inv_lds[r];
            float4 res;
            res.x = (acc[r].x + o.x) * iv;
            res.y = (acc[r].y + o.y) * iv;
            res.z = (acc[r].z + o.z) * iv;
            res.w = (acc[r].w + o.w) * iv;
            *(float4*)&out[(size_t)(b * 512 + q0 + r) * 256 + lane * 4] = res;
        }
    }
}

extern "C" void kernel_launch(void* const* d_in, const int* in_sizes, int n_in,
                              void* d_out, int out_size, void* d_ws, size_t ws_size,
                              hipStream_t stream) {
    const float* query = (const float*)d_in[0];
    const float* value = (const float*)d_in[1];
    const float* Wq    = (const float*)d_in[2];
    const float* Wv    = (const float*)d_in[3];
    const float* scale = (const float*)d_in[4];

    float* out0 = (float*)d_out;                 // [4,512,256]
    float* attn = out0 + 4 * 512 * 256;          // [4,512,512]

    float* eq  = (float*)d_ws;                   // [2048,256]
    float* ekT = eq + 2048 * 256;                // [4,256,512] transposed

    void* args[] = {(void*)&query, (void*)&value, (void*)&Wq, (void*)&Wv,
                    (void*)&scale, (void*)&eq, (void*)&ekT, (void*)&attn,
                    (void*)&out0};
    hipLaunchCooperativeKernel((const void*)mega_kernel, dim3(256), dim3(512),
                               args, 0, stream);
}

// Round 29
// 70.330 us; speedup vs baseline: 2.2325x; 2.2325x over previous
//
#include <hip/hip_runtime.h>

#define LOG2E 1.4426950408889634f
#define TWO_LOG2E 2.885390081777927f

__device__ __forceinline__ float fast_exp2(float x) { return __builtin_amdgcn_exp2f(x); }
__device__ __forceinline__ float fast_rcp(float x)  { return __builtin_amdgcn_rcpf(x); }

// paired-rcp: s0/A + s1/B with A=q0*k0+1, B=q1*k1+1
__device__ __forceinline__ void term2(float s0, float s1, float qx, float qy,
                                      float kx, float ky, float& acc) {
    const float A = fmaf(qx, kx, 1.f);
    const float B = fmaf(qy, ky, 1.f);
    acc = fmaf(fmaf(s1, A, s0 * B), fast_rcp(A * B), acc);
}

// ---------------------------------------------------------------------------
// K1: projections + exp transform, v2 (proven R25: coalesced ekT via LDS
// transpose).
// ---------------------------------------------------------------------------
__global__ __launch_bounds__(256) void proj_kernel(
    const float* __restrict__ query, const float* __restrict__ value,
    const float* __restrict__ Wq, const float* __restrict__ Wv,
    float* __restrict__ eq, float* __restrict__ ekT)
{
    __shared__ float in_lds[8 * 256];   // eq path
    __shared__ float v_lds[64 * 68];    // ek path: value tile
    __shared__ float w_lds[64 * 36];    // ek path: Wv tile
    __shared__ float t_lds[32 * 68];    // ek path: output transpose buffer

    const int t = threadIdx.x;
    const int bx = blockIdx.x;

    if (bx < 256) {
        const int row0 = bx * 8;
        const float4* s4 = (const float4*)(query + (size_t)row0 * 256);
        float4* l4 = (float4*)in_lds;
        l4[t] = s4[t];
        l4[t + 256] = s4[t + 256];
        __syncthreads();

        float acc[8];
#pragma unroll
        for (int r = 0; r < 8; ++r) acc[r] = 0.f;

        for (int d = 0; d < 256; d += 4) {
            const float w0 = Wq[(d + 0) * 256 + t];
            const float w1 = Wq[(d + 1) * 256 + t];
            const float w2 = Wq[(d + 2) * 256 + t];
            const float w3 = Wq[(d + 3) * 256 + t];
#pragma unroll
            for (int r = 0; r < 8; ++r) {
                const float4 v = *(const float4*)&in_lds[r * 256 + d];
                acc[r] = fmaf(v.x, w0, acc[r]);
                acc[r] = fmaf(v.y, w1, acc[r]);
                acc[r] = fmaf(v.z, w2, acc[r]);
                acc[r] = fmaf(v.w, w3, acc[r]);
            }
        }
        float* dst = eq + (size_t)row0 * 256;
#pragma unroll
        for (int r = 0; r < 8; ++r) dst[r * 256 + t] = fast_exp2(acc[r] * TWO_LOG2E);
    } else {
        const int bi = bx - 256;
        const int kt = bi >> 3, dt = bi & 7;
        const int gk0 = kt * 64;
        const int bb = gk0 >> 9, kin0 = gk0 & 511;
        const int dout0 = dt * 32;
        const int kp = t >> 3, dg = t & 7;

        float acc[2][4];
#pragma unroll
        for (int i = 0; i < 2; ++i)
#pragma unroll
            for (int j = 0; j < 4; ++j) acc[i][j] = 0.f;

        for (int dc = 0; dc < 256; dc += 64) {
            __syncthreads();
#pragma unroll
            for (int l = 0; l < 4; ++l) {
                const int idx = t + 256 * l;
                const int r = idx >> 4, c4 = (idx & 15) * 4;
                *(float4*)&v_lds[r * 68 + c4] =
                    *(const float4*)&value[(size_t)(gk0 + r) * 256 + dc + c4];
            }
#pragma unroll
            for (int l = 0; l < 2; ++l) {
                const int idx = t + 256 * l;
                const int r = idx >> 3, c4 = (idx & 7) * 4;
                *(float4*)&w_lds[r * 36 + c4] =
                    *(const float4*)&Wv[(size_t)(dc + r) * 256 + dout0 + c4];
            }
            __syncthreads();

#pragma unroll 8
            for (int din = 0; din < 64; ++din) {
                const float v0 = v_lds[(2 * kp + 0) * 68 + din];
                const float v1 = v_lds[(2 * kp + 1) * 68 + din];
                const float4 wv = *(const float4*)&w_lds[din * 36 + 4 * dg];
                acc[0][0] = fmaf(v0, wv.x, acc[0][0]);
                acc[0][1] = fmaf(v0, wv.y, acc[0][1]);
                acc[0][2] = fmaf(v0, wv.z, acc[0][2]);
                acc[0][3] = fmaf(v0, wv.w, acc[0][3]);
                acc[1][0] = fmaf(v1, wv.x, acc[1][0]);
                acc[1][1] = fmaf(v1, wv.y, acc[1][1]);
                acc[1][2] = fmaf(v1, wv.z, acc[1][2]);
                acc[1][3] = fmaf(v1, wv.w, acc[1][3]);
            }
        }
        __syncthreads();
#pragma unroll
        for (int i = 0; i < 2; ++i)
#pragma unroll
            for (int j = 0; j < 4; ++j)
                t_lds[(4 * dg + j) * 68 + 2 * kp + i] =
                    fast_exp2(acc[i][j] * TWO_LOG2E);
        __syncthreads();
#pragma unroll
        for (int l = 0; l < 2; ++l) {
            const int idx = t + 256 * l;
            const int row = idx >> 4, c4 = (idx & 15) * 4;
            *(float4*)&ekT[(size_t)bb * 131072 + (size_t)(dout0 + row) * 512 + kin0 + c4] =
                *(const float4*)&t_lds[row * 68 + c4];
        }
    }
}

// ---------------------------------------------------------------------------
// K2: FUSED scores + softmax + PV, v14 = R22's 4-q-row geometry with the
// CORRECT register budget. R22 failed because launch_bounds(512,4) capped
// VGPR at 64 -> prefetch rotation dropped. Here launch_bounds(512,2) (cap
// 256; compiler keeps ~90 VGPR rotation, proven R21) + grid 512 = 2
// blocks/CU by LDS (30KB) = 4 waves/SIMD WITH the pipeline intact.
// Block = (b, 4 q-rows), thread = 2q x 2k over full 256 d, depth-1 prefetch.
// ---------------------------------------------------------------------------
#define EQ_ST 260
#define SS_ST 520
__global__ __launch_bounds__(512, 2) void fused_kernel(
    const float* __restrict__ eq, const float* __restrict__ ekT,
    const float* __restrict__ scale, const float* __restrict__ value,
    float* __restrict__ attn, float* __restrict__ out)
{
    __shared__ float eq_lds[4 * EQ_ST];     // 4.2KB
    __shared__ float sc_lds[256];
    __shared__ float s_tile[4 * SS_ST];     // 8.3KB raw scores -> raw exp
    __shared__ float red[4 * 4 * 256];      // 16KB PV reduce buffer
    __shared__ float inv_lds[4];

    const int t = threadIdx.x;
    const int w = t >> 6, lane = t & 63;
    const int qg = w >> 2;                  // 0..1 (2 q-rows each)
    const int kg = ((w & 3) << 6) + lane;   // 0..255 (2 k-cols each)
    const int k0 = 2 * kg;
    const int qt = blockIdx.x, b = blockIdx.y;
    const int q0 = qt * 4;

    // prologue: stage eq (4x256 = 256 float4s) and scale
    if (t < 256) {
        const float4 v = ((const float4*)(eq + (size_t)(b * 512 + q0) * 256))[t];
        const int row = t >> 6, c = t & 63;
        *(float4*)&eq_lds[row * EQ_ST + 4 * c] = v;
    } else {
        sc_lds[t - 256] = -2.f * scale[t - 256];
    }
    __syncthreads();

    // ---- Phase A: scores, full d per thread, NO barriers, pipelined ----
    const float* ekTb = ekT + (size_t)b * 131072 + k0;
    const float* q0r = &eq_lds[(2 * qg + 0) * EQ_ST];
    const float* q1r = &eq_lds[(2 * qg + 1) * EQ_ST];

    float a00 = 0.f, a01 = 0.f, a10 = 0.f, a11 = 0.f;

    // preload iteration d=0
    float4 sv  = *(const float4*)&sc_lds[0];
    float4 qv0 = *(const float4*)&q0r[0];
    float4 qv1 = *(const float4*)&q1r[0];
    float2 k0v = *(const float2*)&ekTb[(size_t)0 * 512];
    float2 k1v = *(const float2*)&ekTb[(size_t)1 * 512];
    float2 k2v = *(const float2*)&ekTb[(size_t)2 * 512];
    float2 k3v = *(const float2*)&ekTb[(size_t)3 * 512];

#pragma unroll 4
    for (int d = 0; d < 256; d += 4) {
        const float4 csv = sv, c0 = qv0, c1 = qv1;
        const float2 ck0 = k0v, ck1 = k1v, ck2 = k2v, ck3 = k3v;

        if (d < 252) {                      // prefetch iteration d+4
            const int dn = d + 4;
            sv  = *(const float4*)&sc_lds[dn];
            qv0 = *(const float4*)&q0r[dn];
            qv1 = *(const float4*)&q1r[dn];
            k0v = *(const float2*)&ekTb[(size_t)(dn + 0) * 512];
            k1v = *(const float2*)&ekTb[(size_t)(dn + 1) * 512];
            k2v = *(const float2*)&ekTb[(size_t)(dn + 2) * 512];
            k3v = *(const float2*)&ekTb[(size_t)(dn + 3) * 512];
        }

        term2(csv.x, csv.y, c0.x, c0.y, ck0.x, ck1.x, a00);
        term2(csv.z, csv.w, c0.z, c0.w, ck2.x, ck3.x, a00);
        term2(csv.x, csv.y, c0.x, c0.y, ck0.y, ck1.y, a01);
        term2(csv.z, csv.w, c0.z, c0.w, ck2.y, ck3.y, a01);

        term2(csv.x, csv.y, c1.x, c1.y, ck0.x, ck1.x, a10);
        term2(csv.z, csv.w, c1.z, c1.w, ck2.x, ck3.x, a10);
        term2(csv.x, csv.y, c1.x, c1.y, ck0.y, ck1.y, a11);
        term2(csv.z, csv.w, c1.z, c1.w, ck2.y, ck3.y, a11);
    }

    // write raw scores (float2 per q-row; lanes 8B apart -> 2-way banks, free)
    *(float2*)&s_tile[(2 * qg + 0) * SS_ST + k0] = make_float2(a00, a01);
    *(float2*)&s_tile[(2 * qg + 1) * SS_ST + k0] = make_float2(a10, a11);
    __syncthreads();

    // ---- Phase B: softmax (waves 0..3, wave = q-row), attn write ----
    if (w < 4) {
        float x[8];
        float m = -1e30f;
#pragma unroll
        for (int j = 0; j < 8; ++j) {
            x[j] = s_tile[w * SS_ST + 64 * j + lane];
            m = fmaxf(m, x[j]);
        }
#pragma unroll
        for (int off = 32; off; off >>= 1) m = fmaxf(m, __shfl_xor(m, off));

        float sum = 0.f;
#pragma unroll
        for (int j = 0; j < 8; ++j) { x[j] = fast_exp2((x[j] - m) * LOG2E); sum += x[j]; }
#pragma unroll
        for (int off = 32; off; off >>= 1) sum += __shfl_xor(sum, off);
        const float inv = fast_rcp(sum);

        float* arow = attn + (size_t)(b * 512 + q0 + w) * 512;
#pragma unroll
        for (int j = 0; j < 8; ++j) {
            s_tile[w * SS_ST + 64 * j + lane] = x[j];   // raw exp for PV
            arow[64 * j + lane] = x[j] * inv;
        }
        if (lane == 0) inv_lds[w] = inv;
    }
    __syncthreads();

    // ---- Phase C: PV, wave w owns k in [64w, 64w+64) ----
    float4 acc[4];
#pragma unroll
    for (int r = 0; r < 4; ++r) acc[r] = make_float4(0.f, 0.f, 0.f, 0.f);

    const float* vbase = value + (size_t)(b * 512 + 64 * w) * 256;
    for (int k4 = 0; k4 < 64; k4 += 4) {
        const float4 v0 = *(const float4*)&vbase[(k4 + 0) * 256 + lane * 4];
        const float4 v1 = *(const float4*)&vbase[(k4 + 1) * 256 + lane * 4];
        const float4 v2 = *(const float4*)&vbase[(k4 + 2) * 256 + lane * 4];
        const float4 v3 = *(const float4*)&vbase[(k4 + 3) * 256 + lane * 4];
#pragma unroll
        for (int r = 0; r < 4; ++r) {
            const float4 s4 = *(const float4*)&s_tile[r * SS_ST + 64 * w + k4];
            acc[r].x = fmaf(s4.x, v0.x, acc[r].x); acc[r].y = fmaf(s4.x, v0.y, acc[r].y);
            acc[r].z = fmaf(s4.x, v0.z, acc[r].z); acc[r].w = fmaf(s4.x, v0.w, acc[r].w);
            acc[r].x = fmaf(s4.y, v1.x, acc[r].x); acc[r].y = fmaf(s4.y, v1.y, acc[r].y);
            acc[r].z = fmaf(s4.y, v1.z, acc[r].z); acc[r].w = fmaf(s4.y, v1.w, acc[r].w);
            acc[r].x = fmaf(s4.z, v2.x, acc[r].x); acc[r].y = fmaf(s4.z, v2.y, acc[r].y);
            acc[r].z = fmaf(s4.z, v2.z, acc[r].z); acc[r].w = fmaf(s4.z, v2.w, acc[r].w);
            acc[r].x = fmaf(s4.w, v3.x, acc[r].x); acc[r].y = fmaf(s4.w, v3.y, acc[r].y);
            acc[r].z = fmaf(s4.w, v3.z, acc[r].z); acc[r].w = fmaf(s4.w, v3.w, acc[r].w);
        }
    }

    // ---- Phase D: tree reduce 8 -> 1 ----
    if (w >= 4) {
#pragma unroll
        for (int r = 0; r < 4; ++r)
            *(float4*)&red[((w - 4) * 4 + r) * 256 + lane * 4] = acc[r];
    }
    __syncthreads();
    if (w < 4) {
#pragma unroll
        for (int r = 0; r < 4; ++r) {
            const float4 o = *(const float4*)&red[(w * 4 + r) * 256 + lane * 4];
            acc[r].x += o.x; acc[r].y += o.y; acc[r].z += o.z; acc[r].w += o.w;
        }
    }
    __syncthreads();
    if (w >= 2 && w < 4) {
#pragma unroll
        for (int r = 0; r < 4; ++r)
            *(float4*)&red[((w - 2) * 4 + r) * 256 + lane * 4] = acc[r];
    }
    __syncthreads();
    if (w < 2) {
#pragma unroll
        for (int r = 0; r < 4; ++r) {
            const float4 o = *(const float4*)&red[(w * 4 + r) * 256 + lane * 4];
            acc[r].x += o.x; acc[r].y += o.y; acc[r].z += o.z; acc[r].w += o.w;
        }
    }
    __syncthreads();
    if (w == 1) {
#pragma unroll
        for (int r = 0; r < 4; ++r)
            *(float4*)&red[r * 256 + lane * 4] = acc[r];
    }
    __syncthreads();
    if (w == 0) {
#pragma unroll
        for (int r = 0; r < 4; ++r) {
            const float4 o = *(const float4*)&red[r * 256 + lane * 4];
            const float iv = inv_lds[r];
            float4 res;
            res.x = (acc[r].x + o.x) * iv;
            res.y = (acc[r].y + o.y) * iv;
            res.z = (acc[r].z + o.z) * iv;
            res.w = (acc[r].w + o.w) * iv;
            *(float4*)&out[(size_t)(b * 512 + q0 + r) * 256 + lane * 4] = res;
        }
    }
}

extern "C" void kernel_launch(void* const* d_in, const int* in_sizes, int n_in,
                              void* d_out, int out_size, void* d_ws, size_t ws_size,
                              hipStream_t stream) {
    const float* query = (const float*)d_in[0];
    const float* value = (const float*)d_in[1];
    const float* Wq    = (const float*)d_in[2];
    const float* Wv    = (const float*)d_in[3];
    const float* scale = (const float*)d_in[4];

    float* out0 = (float*)d_out;                 // [4,512,256]
    float* attn = out0 + 4 * 512 * 256;          // [4,512,512]

    float* eq  = (float*)d_ws;                   // [2048,256]
    float* ekT = eq + 2048 * 256;                // [4,256,512] transposed

    proj_kernel<<<512, 256, 0, stream>>>(query, value, Wq, Wv, eq, ekT);
    fused_kernel<<<dim3(128, 4), 512, 0, stream>>>(eq, ekT, scale, value, attn, out0);
}

// Round 30
// 61.405 us; speedup vs baseline: 2.5570x; 1.1453x over previous
//
#include <hip/hip_runtime.h>

#define LOG2E 1.4426950408889634f
#define TWO_LOG2E 2.885390081777927f

__device__ __forceinline__ float fast_exp2(float x) { return __builtin_amdgcn_exp2f(x); }
__device__ __forceinline__ float fast_rcp(float x)  { return __builtin_amdgcn_rcpf(x); }

// paired-rcp: s0/A + s1/B with A=q0*k0+1, B=q1*k1+1
__device__ __forceinline__ void term2(float s0, float s1, float qx, float qy,
                                      float kx, float ky, float& acc) {
    const float A = fmaf(qx, kx, 1.f);
    const float B = fmaf(qy, ky, 1.f);
    acc = fmaf(fmaf(s1, A, s0 * B), fast_rcp(A * B), acc);
}

// ---------------------------------------------------------------------------
// K1: projections + exp transform, v2 (proven R25).
// Blocks 0..255: eq path. Blocks 256..511: ekT tiled GEMM with transposed
// output through LDS (coalesced 256B rows).
// ---------------------------------------------------------------------------
__global__ __launch_bounds__(256) void proj_kernel(
    const float* __restrict__ query, const float* __restrict__ value,
    const float* __restrict__ Wq, const float* __restrict__ Wv,
    float* __restrict__ eq, float* __restrict__ ekT)
{
    __shared__ float in_lds[8 * 256];   // eq path
    __shared__ float v_lds[64 * 68];    // ek path: value tile
    __shared__ float w_lds[64 * 36];    // ek path: Wv tile
    __shared__ float t_lds[32 * 68];    // ek path: output transpose buffer

    const int t = threadIdx.x;
    const int bx = blockIdx.x;

    if (bx < 256) {
        const int row0 = bx * 8;
        const float4* s4 = (const float4*)(query + (size_t)row0 * 256);
        float4* l4 = (float4*)in_lds;
        l4[t] = s4[t];
        l4[t + 256] = s4[t + 256];
        __syncthreads();

        float acc[8];
#pragma unroll
        for (int r = 0; r < 8; ++r) acc[r] = 0.f;

        for (int d = 0; d < 256; d += 4) {
            const float w0 = Wq[(d + 0) * 256 + t];
            const float w1 = Wq[(d + 1) * 256 + t];
            const float w2 = Wq[(d + 2) * 256 + t];
            const float w3 = Wq[(d + 3) * 256 + t];
#pragma unroll
            for (int r = 0; r < 8; ++r) {
                const float4 v = *(const float4*)&in_lds[r * 256 + d];
                acc[r] = fmaf(v.x, w0, acc[r]);
                acc[r] = fmaf(v.y, w1, acc[r]);
                acc[r] = fmaf(v.z, w2, acc[r]);
                acc[r] = fmaf(v.w, w3, acc[r]);
            }
        }
        float* dst = eq + (size_t)row0 * 256;
#pragma unroll
        for (int r = 0; r < 8; ++r) dst[r * 256 + t] = fast_exp2(acc[r] * TWO_LOG2E);
    } else {
        const int bi = bx - 256;
        const int kt = bi >> 3, dt = bi & 7;
        const int gk0 = kt * 64;
        const int bb = gk0 >> 9, kin0 = gk0 & 511;
        const int dout0 = dt * 32;
        const int kp = t >> 3, dg = t & 7;

        float acc[2][4];
#pragma unroll
        for (int i = 0; i < 2; ++i)
#pragma unroll
            for (int j = 0; j < 4; ++j) acc[i][j] = 0.f;

        for (int dc = 0; dc < 256; dc += 64) {
            __syncthreads();
#pragma unroll
            for (int l = 0; l < 4; ++l) {
                const int idx = t + 256 * l;
                const int r = idx >> 4, c4 = (idx & 15) * 4;
                *(float4*)&v_lds[r * 68 + c4] =
                    *(const float4*)&value[(size_t)(gk0 + r) * 256 + dc + c4];
            }
#pragma unroll
            for (int l = 0; l < 2; ++l) {
                const int idx = t + 256 * l;
                const int r = idx >> 3, c4 = (idx & 7) * 4;
                *(float4*)&w_lds[r * 36 + c4] =
                    *(const float4*)&Wv[(size_t)(dc + r) * 256 + dout0 + c4];
            }
            __syncthreads();

#pragma unroll 8
            for (int din = 0; din < 64; ++din) {
                const float v0 = v_lds[(2 * kp + 0) * 68 + din];
                const float v1 = v_lds[(2 * kp + 1) * 68 + din];
                const float4 wv = *(const float4*)&w_lds[din * 36 + 4 * dg];
                acc[0][0] = fmaf(v0, wv.x, acc[0][0]);
                acc[0][1] = fmaf(v0, wv.y, acc[0][1]);
                acc[0][2] = fmaf(v0, wv.z, acc[0][2]);
                acc[0][3] = fmaf(v0, wv.w, acc[0][3]);
                acc[1][0] = fmaf(v1, wv.x, acc[1][0]);
                acc[1][1] = fmaf(v1, wv.y, acc[1][1]);
                acc[1][2] = fmaf(v1, wv.z, acc[1][2]);
                acc[1][3] = fmaf(v1, wv.w, acc[1][3]);
            }
        }
        __syncthreads();
#pragma unroll
        for (int i = 0; i < 2; ++i)
#pragma unroll
            for (int j = 0; j < 4; ++j)
                t_lds[(4 * dg + j) * 68 + 2 * kp + i] =
                    fast_exp2(acc[i][j] * TWO_LOG2E);
        __syncthreads();
#pragma unroll
        for (int l = 0; l < 2; ++l) {
            const int idx = t + 256 * l;
            const int row = idx >> 4, c4 = (idx & 15) * 4;
            *(float4*)&ekT[(size_t)bb * 131072 + (size_t)(dout0 + row) * 512 + kin0 + c4] =
                *(const float4*)&t_lds[row * 68 + c4];
        }
    }
}

// ---------------------------------------------------------------------------
// K2: FUSED scores + softmax + PV (v12, best measured: 44.2us, VGPR 100,
// 0 bank conflicts, refchecked). Depth-2 pipelined, 8 q-rows, 512 thr.
// ---------------------------------------------------------------------------
#define EQ_ST 260
#define SS_ST 520
__global__ __launch_bounds__(512, 2) void fused_kernel(
    const float* __restrict__ eq, const float* __restrict__ ekT,
    const float* __restrict__ scale, const float* __restrict__ value,
    float* __restrict__ attn, float* __restrict__ out)
{
    __shared__ float eq_lds[8 * EQ_ST];     // 8.3KB
    __shared__ float sc_lds[256];
    __shared__ float s_tile[8 * SS_ST];     // 16.6KB raw scores -> raw exp
    __shared__ float red[4 * 8 * 256];      // 32KB PV reduce buffer
    __shared__ float inv_lds[8];

    const int t = threadIdx.x;
    const int w = t >> 6, lane = t & 63;
    const int qg = w >> 2;                  // 0..1 (4 q-rows each)
    const int kg = ((w & 3) << 6) + lane;   // 0..255 (2 k-cols each)
    const int k0 = 2 * kg;
    const int qt = blockIdx.x, b = blockIdx.y;
    const int q0 = qt * 8;

    // prologue: stage eq (8x256 = 512 float4s, 1/thread) and scale
    {
        const int row = t >> 6, c = t & 63;
        const float4 v = ((const float4*)(eq + (size_t)(b * 512 + q0) * 256))[row * 64 + c];
        *(float4*)&eq_lds[row * EQ_ST + 4 * c] = v;
    }
    if (t < 256) sc_lds[t] = -2.f * scale[t];
    __syncthreads();

    // ---- Phase A: scores, full d, NO barriers, depth-2 pipeline ----
    const float* ekTb = ekT + (size_t)b * 131072 + k0;
    const float* q0r = &eq_lds[(4 * qg + 0) * EQ_ST];
    const float* q1r = &eq_lds[(4 * qg + 1) * EQ_ST];
    const float* q2r = &eq_lds[(4 * qg + 2) * EQ_ST];
    const float* q3r = &eq_lds[(4 * qg + 3) * EQ_ST];

    float a00 = 0.f, a01 = 0.f, a10 = 0.f, a11 = 0.f;
    float a20 = 0.f, a21 = 0.f, a30 = 0.f, a31 = 0.f;

    float4 svA  = *(const float4*)&sc_lds[0];
    float4 qv0A = *(const float4*)&q0r[0];
    float4 qv1A = *(const float4*)&q1r[0];
    float4 qv2A = *(const float4*)&q2r[0];
    float4 qv3A = *(const float4*)&q3r[0];
    float2 k0A = *(const float2*)&ekTb[(size_t)0 * 512];
    float2 k1A = *(const float2*)&ekTb[(size_t)1 * 512];
    float2 k2A = *(const float2*)&ekTb[(size_t)2 * 512];
    float2 k3A = *(const float2*)&ekTb[(size_t)3 * 512];

    float4 svB  = *(const float4*)&sc_lds[4];
    float4 qv0B = *(const float4*)&q0r[4];
    float4 qv1B = *(const float4*)&q1r[4];
    float4 qv2B = *(const float4*)&q2r[4];
    float4 qv3B = *(const float4*)&q3r[4];
    float2 k0B = *(const float2*)&ekTb[(size_t)4 * 512];
    float2 k1B = *(const float2*)&ekTb[(size_t)5 * 512];
    float2 k2B = *(const float2*)&ekTb[(size_t)6 * 512];
    float2 k3B = *(const float2*)&ekTb[(size_t)7 * 512];

#pragma unroll 2
    for (int d = 0; d < 256; d += 8) {
        {
            const float4 csv = svA, c0 = qv0A, c1 = qv1A, c2 = qv2A, c3 = qv3A;
            const float2 ck0 = k0A, ck1 = k1A, ck2 = k2A, ck3 = k3A;
            if (d < 248) {
                const int dn = d + 8;
                svA  = *(const float4*)&sc_lds[dn];
                qv0A = *(const float4*)&q0r[dn];
                qv1A = *(const float4*)&q1r[dn];
                qv2A = *(const float4*)&q2r[dn];
                qv3A = *(const float4*)&q3r[dn];
                k0A = *(const float2*)&ekTb[(size_t)(dn + 0) * 512];
                k1A = *(const float2*)&ekTb[(size_t)(dn + 1) * 512];
                k2A = *(const float2*)&ekTb[(size_t)(dn + 2) * 512];
                k3A = *(const float2*)&ekTb[(size_t)(dn + 3) * 512];
            }
            term2(csv.x, csv.y, c0.x, c0.y, ck0.x, ck1.x, a00);
            term2(csv.z, csv.w, c0.z, c0.w, ck2.x, ck3.x, a00);
            term2(csv.x, csv.y, c0.x, c0.y, ck0.y, ck1.y, a01);
            term2(csv.z, csv.w, c0.z, c0.w, ck2.y, ck3.y, a01);
            term2(csv.x, csv.y, c1.x, c1.y, ck0.x, ck1.x, a10);
            term2(csv.z, csv.w, c1.z, c1.w, ck2.x, ck3.x, a10);
            term2(csv.x, csv.y, c1.x, c1.y, ck0.y, ck1.y, a11);
            term2(csv.z, csv.w, c1.z, c1.w, ck2.y, ck3.y, a11);
            term2(csv.x, csv.y, c2.x, c2.y, ck0.x, ck1.x, a20);
            term2(csv.z, csv.w, c2.z, c2.w, ck2.x, ck3.x, a20);
            term2(csv.x, csv.y, c2.x, c2.y, ck0.y, ck1.y, a21);
            term2(csv.z, csv.w, c2.z, c2.w, ck2.y, ck3.y, a21);
            term2(csv.x, csv.y, c3.x, c3.y, ck0.x, ck1.x, a30);
            term2(csv.z, csv.w, c3.z, c3.w, ck2.x, ck3.x, a30);
            term2(csv.x, csv.y, c3.x, c3.y, ck0.y, ck1.y, a31);
            term2(csv.z, csv.w, c3.z, c3.w, ck2.y, ck3.y, a31);
        }
        {
            const float4 csv = svB, c0 = qv0B, c1 = qv1B, c2 = qv2B, c3 = qv3B;
            const float2 ck0 = k0B, ck1 = k1B, ck2 = k2B, ck3 = k3B;
            if (d < 244) {
                const int dn = d + 12;
                svB  = *(const float4*)&sc_lds[dn];
                qv0B = *(const float4*)&q0r[dn];
                qv1B = *(const float4*)&q1r[dn];
                qv2B = *(const float4*)&q2r[dn];
                qv3B = *(const float4*)&q3r[dn];
                k0B = *(const float2*)&ekTb[(size_t)(dn + 0) * 512];
                k1B = *(const float2*)&ekTb[(size_t)(dn + 1) * 512];
                k2B = *(const float2*)&ekTb[(size_t)(dn + 2) * 512];
                k3B = *(const float2*)&ekTb[(size_t)(dn + 3) * 512];
            }
            term2(csv.x, csv.y, c0.x, c0.y, ck0.x, ck1.x, a00);
            term2(csv.z, csv.w, c0.z, c0.w, ck2.x, ck3.x, a00);
            term2(csv.x, csv.y, c0.x, c0.y, ck0.y, ck1.y, a01);
            term2(csv.z, csv.w, c0.z, c0.w, ck2.y, ck3.y, a01);
            term2(csv.x, csv.y, c1.x, c1.y, ck0.x, ck1.x, a10);
            term2(csv.z, csv.w, c1.z, c1.w, ck2.x, ck3.x, a10);
            term2(csv.x, csv.y, c1.x, c1.y, ck0.y, ck1.y, a11);
            term2(csv.z, csv.w, c1.z, c1.w, ck2.y, ck3.y, a11);
            term2(csv.x, csv.y, c2.x, c2.y, ck0.x, ck1.x, a20);
            term2(csv.z, csv.w, c2.z, c2.w, ck2.x, ck3.x, a20);
            term2(csv.x, csv.y, c2.x, c2.y, ck0.y, ck1.y, a21);
            term2(csv.z, csv.w, c2.z, c2.w, ck2.y, ck3.y, a21);
            term2(csv.x, csv.y, c3.x, c3.y, ck0.x, ck1.x, a30);
            term2(csv.z, csv.w, c3.z, c3.w, ck2.x, ck3.x, a30);
            term2(csv.x, csv.y, c3.x, c3.y, ck0.y, ck1.y, a31);
            term2(csv.z, csv.w, c3.z, c3.w, ck2.y, ck3.y, a31);
        }
    }

    *(float2*)&s_tile[(4 * qg + 0) * SS_ST + k0] = make_float2(a00, a01);
    *(float2*)&s_tile[(4 * qg + 1) * SS_ST + k0] = make_float2(a10, a11);
    *(float2*)&s_tile[(4 * qg + 2) * SS_ST + k0] = make_float2(a20, a21);
    *(float2*)&s_tile[(4 * qg + 3) * SS_ST + k0] = make_float2(a30, a31);
    __syncthreads();

    // ---- Phase B: softmax (wave w = q-row w), attn write ----
    {
        float x[8];
        float m = -1e30f;
#pragma unroll
        for (int j = 0; j < 8; ++j) {
            x[j] = s_tile[w * SS_ST + 64 * j + lane];
            m = fmaxf(m, x[j]);
        }
#pragma unroll
        for (int off = 32; off; off >>= 1) m = fmaxf(m, __shfl_xor(m, off));

        float sum = 0.f;
#pragma unroll
        for (int j = 0; j < 8; ++j) { x[j] = fast_exp2((x[j] - m) * LOG2E); sum += x[j]; }
#pragma unroll
        for (int off = 32; off; off >>= 1) sum += __shfl_xor(sum, off);
        const float inv = fast_rcp(sum);

        float* arow = attn + (size_t)(b * 512 + q0 + w) * 512;
#pragma unroll
        for (int j = 0; j < 8; ++j) {
            s_tile[w * SS_ST + 64 * j + lane] = x[j];   // raw exp for PV
            arow[64 * j + lane] = x[j] * inv;
        }
        if (lane == 0) inv_lds[w] = inv;
    }
    __syncthreads();

    // ---- Phase C: PV, wave w owns k in [64w, 64w+64) ----
    float4 acc[8];
#pragma unroll
    for (int r = 0; r < 8; ++r) acc[r] = make_float4(0.f, 0.f, 0.f, 0.f);

    const float* vbase = value + (size_t)(b * 512 + 64 * w) * 256;
    for (int k4 = 0; k4 < 64; k4 += 4) {
        const float4 v0 = *(const float4*)&vbase[(k4 + 0) * 256 + lane * 4];
        const float4 v1 = *(const float4*)&vbase[(k4 + 1) * 256 + lane * 4];
        const float4 v2 = *(const float4*)&vbase[(k4 + 2) * 256 + lane * 4];
        const float4 v3 = *(const float4*)&vbase[(k4 + 3) * 256 + lane * 4];
#pragma unroll
        for (int r = 0; r < 8; ++r) {
            const float4 s4 = *(const float4*)&s_tile[r * SS_ST + 64 * w + k4];
            acc[r].x = fmaf(s4.x, v0.x, acc[r].x); acc[r].y = fmaf(s4.x, v0.y, acc[r].y);
            acc[r].z = fmaf(s4.x, v0.z, acc[r].z); acc[r].w = fmaf(s4.x, v0.w, acc[r].w);
            acc[r].x = fmaf(s4.y, v1.x, acc[r].x); acc[r].y = fmaf(s4.y, v1.y, acc[r].y);
            acc[r].z = fmaf(s4.y, v1.z, acc[r].z); acc[r].w = fmaf(s4.y, v1.w, acc[r].w);
            acc[r].x = fmaf(s4.z, v2.x, acc[r].x); acc[r].y = fmaf(s4.z, v2.y, acc[r].y);
            acc[r].z = fmaf(s4.z, v2.z, acc[r].z); acc[r].w = fmaf(s4.z, v2.w, acc[r].w);
            acc[r].x = fmaf(s4.w, v3.x, acc[r].x); acc[r].y = fmaf(s4.w, v3.y, acc[r].y);
            acc[r].z = fmaf(s4.w, v3.z, acc[r].z); acc[r].w = fmaf(s4.w, v3.w, acc[r].w);
        }
    }

    // ---- Phase D: tree reduce 8 -> 1 ----
    if (w >= 4) {
#pragma unroll
        for (int r = 0; r < 8; ++r)
            *(float4*)&red[((w - 4) * 8 + r) * 256 + lane * 4] = acc[r];
    }
    __syncthreads();
    if (w < 4) {
#pragma unroll
        for (int r = 0; r < 8; ++r) {
            const float4 o = *(const float4*)&red[(w * 8 + r) * 256 + lane * 4];
            acc[r].x += o.x; acc[r].y += o.y; acc[r].z += o.z; acc[r].w += o.w;
        }
    }
    __syncthreads();
    if (w >= 2 && w < 4) {
#pragma unroll
        for (int r = 0; r < 8; ++r)
            *(float4*)&red[((w - 2) * 8 + r) * 256 + lane * 4] = acc[r];
    }
    __syncthreads();
    if (w < 2) {
#pragma unroll
        for (int r = 0; r < 8; ++r) {
            const float4 o = *(const float4*)&red[(w * 8 + r) * 256 + lane * 4];
            acc[r].x += o.x; acc[r].y += o.y; acc[r].z += o.z; acc[r].w += o.w;
        }
    }
    __syncthreads();
    if (w == 1) {
#pragma unroll
        for (int r = 0; r < 8; ++r)
            *(float4*)&red[r * 256 + lane * 4] = acc[r];
    }
    __syncthreads();
    if (w == 0) {
#pragma unroll
        for (int r = 0; r < 8; ++r) {
            const float4 o = *(const float4*)&red[r * 256 + lane * 4];
            const float iv = inv_lds[r];
            float4 res;
            res.x = (acc[r].x + o.x) * iv;
            res.y = (acc[r].y + o.y) * iv;
            res.z = (acc[r].z + o.z) * iv;
            res.w = (acc[r].w + o.w) * iv;
            *(float4*)&out[(size_t)(b * 512 + q0 + r) * 256 + lane * 4] = res;
        }
    }
}

extern "C" void kernel_launch(void* const* d_in, const int* in_sizes, int n_in,
                              void* d_out, int out_size, void* d_ws, size_t ws_size,
                              hipStream_t stream) {
    const float* query = (const float*)d_in[0];
    const float* value = (const float*)d_in[1];
    const float* Wq    = (const float*)d_in[2];
    const float* Wv    = (const float*)d_in[3];
    const float* scale = (const float*)d_in[4];

    float* out0 = (float*)d_out;                 // [4,512,256]
    float* attn = out0 + 4 * 512 * 256;          // [4,512,512]

    float* eq  = (float*)d_ws;                   // [2048,256]
    float* ekT = eq + 2048 * 256;                // [4,256,512] transposed

    proj_kernel<<<512, 256, 0, stream>>>(query, value, Wq, Wv, eq, ekT);
    fused_kernel<<<dim3(64, 4), 512, 0, stream>>>(eq, ekT, scale, value, attn, out0);
}